// Round 1
// 1107.538 us; speedup vs baseline: 1.5650x; 1.5650x over previous
//
#include <hip/hip_runtime.h>
#include <hip/hip_bf16.h>
#include <math.h>

#define B_    32
#define T_    32
#define L_    64
#define EMB_  256
#define HID_  512
#define G4_   2048   // 4*HID
#define V_    30000
#define NOBJ_ 91
#define NROWS 1024   // T_*B_

#define NBLK_LSTM 256u
#define NLEAF_    16u
#define BLK_PER_LEAF_ 16u
// bar layout (unsigned words): leaf[l] at bar[l*16] (64B apart), root at bar[256],
// gen at bar[272] (own cacheline). Total 320 words = 1280 B.

__device__ __forceinline__ float sigmoidf_(float x) { return 1.0f / (1.0f + expf(-x)); }

// Fence-free tree grid barrier. All counters are MONOTONIC (no resets): at step t
// each of 256 blocks adds 1 to its leaf (16 leaves x 16 blocks, separate
// cachelines); the leaf-last (sees (t+1)*16) adds 1 to the root; the root-last
// (sees (t+1)*16) stores gen = t+1. Everything RELAXED at AGENT scope: sc1 ops
// are individually coherent at the fabric point, so no buffer_wbl2/buffer_inv is
// ever emitted (the old ACQ_REL arrival + ACQUIRE-per-poll spin generated an L2
// writeback/invalidate storm = ~28us/step). Ordering: __syncthreads drains
// vmcnt(0) per wave, so every block's sc1 hT stores are globally complete before
// its arrival RMW is issued; gen is data-dependent on the root RMW result.
__device__ __forceinline__ void grid_barrier_tree(unsigned* bar, unsigned t) {
  __syncthreads();
  if (threadIdx.x == 0) {
    const unsigned target = t + 1u;
    asm volatile("s_waitcnt vmcnt(0)" ::: "memory");  // belt-and-braces; usually already 0
    unsigned* lc = bar + (blockIdx.x & (NLEAF_ - 1u)) * 16u;
    unsigned a = __hip_atomic_fetch_add(lc, 1u, __ATOMIC_RELAXED, __HIP_MEMORY_SCOPE_AGENT) + 1u;
    if (a == target * BLK_PER_LEAF_) {
      unsigned r = __hip_atomic_fetch_add(bar + 256, 1u, __ATOMIC_RELAXED, __HIP_MEMORY_SCOPE_AGENT) + 1u;
      if (r == target * NLEAF_) {
        __hip_atomic_store(bar + 272, target, __ATOMIC_RELAXED, __HIP_MEMORY_SCOPE_AGENT);
      }
    }
    unsigned cur;
    do {
      __builtin_amdgcn_s_sleep(1);
      cur = __hip_atomic_load(bar + 272, __ATOMIC_RELAXED, __HIP_MEMORY_SCOPE_AGENT);
    } while (cur < target);
  }
  __syncthreads();
}

// ---------------- kernel 1: gather embeddings, time-major X[n][256], n = t*32+b
__global__ void k_gather(const float* __restrict__ features,
                         const int*   __restrict__ captions,
                         const float* __restrict__ embed_W,
                         float* __restrict__ X) {
  int n = blockIdx.x, e = threadIdx.x;          // 1024 blocks x 256 threads
  int t = n >> 5, b = n & 31;
  float v;
  if (t == 0) v = features[b * EMB_ + e];
  else        v = embed_W[captions[b * T_ + (t - 1)] * EMB_ + e];
  X[n * EMB_ + e] = v;
}

// ---------------- generic tiled f32 GEMM: C[M,N] = A[M,K] @ B[N,K]^T (+bias1[n]+bias2[n])
__global__ void k_gemm_bt(const float* __restrict__ A, const float* __restrict__ Bm,
                          const float* __restrict__ bias1, const float* __restrict__ bias2,
                          float* __restrict__ C, int M, int N, int K) {
  __shared__ float As[32][68];
  __shared__ float Bs[32][68];
  int tid = threadIdx.x;
  int tx = tid & 15, ty = tid >> 4;
  int n0 = blockIdx.x * 64, m0 = blockIdx.y * 64;
  float acc[4][4] = {};
  for (int k0 = 0; k0 < K; k0 += 32) {
    #pragma unroll
    for (int rep = 0; rep < 2; ++rep) {
      int idx = rep * 256 + tid;          // [0,512)
      int row = idx >> 3, kq = (idx & 7) * 4;
      float4 a4 = *(const float4*)&A[(m0 + row) * K + k0 + kq];
      As[kq + 0][row] = a4.x; As[kq + 1][row] = a4.y;
      As[kq + 2][row] = a4.z; As[kq + 3][row] = a4.w;
      float4 b4 = *(const float4*)&Bm[(n0 + row) * K + k0 + kq];
      Bs[kq + 0][row] = b4.x; Bs[kq + 1][row] = b4.y;
      Bs[kq + 2][row] = b4.z; Bs[kq + 3][row] = b4.w;
    }
    __syncthreads();
    #pragma unroll
    for (int k = 0; k < 32; ++k) {
      float4 a4 = *(const float4*)&As[k][ty * 4];
      float4 b4 = *(const float4*)&Bs[k][tx * 4];
      float av[4] = {a4.x, a4.y, a4.z, a4.w};
      float bv[4] = {b4.x, b4.y, b4.z, b4.w};
      #pragma unroll
      for (int i = 0; i < 4; ++i)
        #pragma unroll
        for (int j = 0; j < 4; ++j)
          acc[i][j] += av[i] * bv[j];
    }
    __syncthreads();
  }
  int nn = n0 + tx * 4;
  float bb[4] = {0.f, 0.f, 0.f, 0.f};
  if (bias1) {
    #pragma unroll
    for (int j = 0; j < 4; ++j) bb[j] += bias1[nn + j];
  }
  if (bias2) {
    #pragma unroll
    for (int j = 0; j < 4; ++j) bb[j] += bias2[nn + j];
  }
  #pragma unroll
  for (int i = 0; i < 4; ++i) {
    int m = m0 + ty * 4 + i;
    float4 o;
    o.x = acc[i][0] + bb[0]; o.y = acc[i][1] + bb[1];
    o.z = acc[i][2] + bb[2]; o.w = acc[i][3] + bb[3];
    *(float4*)&C[m * N + nn] = o;
  }
}

// ---------------- cooperative persistent LSTM. Cross-step h state moves entirely
// through relaxed AGENT-scope (sc1) atomics: stores in phase D, 8B loads in
// phase B. No plain-cached copy of hT ever exists, so no invalidates are needed.
__global__ __launch_bounds__(256) void k_lstm_coop(
    const float* __restrict__ Xg,    // [1024][2048] input gates (time-major)
    const float* __restrict__ W_hh,  // [2048][512]
    float* __restrict__ hTbuf,       // [2][512][32]
    float* __restrict__ hs,          // [1024][512]
    unsigned* __restrict__ bar) {
  __shared__ float wt_s[512 * 8];        // [k][q], 16 KB
  __shared__ float gredw[4 * 8 * 32];    // [wave][q][b], 4 KB
  const int m = blockIdx.x;
  const int j0 = 2 * m;
  const int tid = threadIdx.x;
  const int kc = tid >> 4;          // [0,16) k-chunk (interleaved k = kk*16+kc)
  const int rg = (tid >> 3) & 1;    // [0,2)  row half (rows rg*4 .. rg*4+3)
  const int bg = tid & 7;           // [0,8)  b quad (b = 4*bg .. 4*bg+3)
  const int jj = tid >> 5, bb = tid & 31;   // phase-D coords (tid < 64)

  // stage weight slice once: wt_s[k*8 + q] = W_hh[(q>>1)*512 + j0 + (q&1)][k]
  {
    int q = tid >> 5, lane = tid & 31;
    const float* src = W_hh + (size_t)((q >> 1) * 512 + j0 + (q & 1)) * HID_;
    for (int kk = 0; kk < 16; ++kk) {
      int k = kk * 32 + lane;
      wt_s[k * 8 + q] = src[k];
    }
  }
  __syncthreads();

  float c = 0.0f;
  for (int t = 0; t < T_; ++t) {
    const float* hTcur = hTbuf + (t & 1) * (HID_ * B_);
    float* hTnext      = hTbuf + ((t + 1) & 1) * (HID_ * B_);
    float xg0 = 0.f, xg1 = 0.f, xg2 = 0.f, xg3 = 0.f;
    if (tid < 64) {
      const float* xp = Xg + (size_t)(t * B_ + bb) * G4_ + j0 + jj;
      xg0 = xp[0]; xg1 = xp[512]; xg2 = xp[1024]; xg3 = xp[1536];
    }
    // phase B: partial GEMM. acc[j][i]: row rg*4+j, batch 4*bg+i, k = kk*16+kc
    float acc[4][4] = {};
    if (t > 0) {
      #pragma unroll 4
      for (int kk = 0; kk < 32; ++kk) {
        const unsigned long long* hp =
            (const unsigned long long*)&hTcur[kk * 512 + kc * 32 + 4 * bg];
        unsigned long long u0 = __hip_atomic_load(hp,     __ATOMIC_RELAXED, __HIP_MEMORY_SCOPE_AGENT);
        unsigned long long u1 = __hip_atomic_load(hp + 1, __ATOMIC_RELAXED, __HIP_MEMORY_SCOPE_AGENT);
        union { unsigned long long u; float f[2]; } c0, c1;
        c0.u = u0; c1.u = u1;
        float hx = c0.f[0], hy = c0.f[1], hz = c1.f[0], hw = c1.f[1];
        float4 w4 = *(const float4*)&wt_s[(kk * 16 + kc) * 8 + 4 * rg];
        acc[0][0] += w4.x * hx; acc[0][1] += w4.x * hy; acc[0][2] += w4.x * hz; acc[0][3] += w4.x * hw;
        acc[1][0] += w4.y * hx; acc[1][1] += w4.y * hy; acc[1][2] += w4.y * hz; acc[1][3] += w4.y * hw;
        acc[2][0] += w4.z * hx; acc[2][1] += w4.z * hy; acc[2][2] += w4.z * hz; acc[2][3] += w4.z * hw;
        acc[3][0] += w4.w * hx; acc[3][1] += w4.w * hy; acc[3][2] += w4.w * hz; acc[3][3] += w4.w * hw;
      }
    }
    // phase C: reduce the 4 in-wave k-chunks (lanes differ in bits 4..5)
    #pragma unroll
    for (int j = 0; j < 4; ++j)
      #pragma unroll
      for (int i = 0; i < 4; ++i) {
        acc[j][i] += __shfl_xor(acc[j][i], 16);
        acc[j][i] += __shfl_xor(acc[j][i], 32);
      }
    if ((tid & 63) < 16) {
      int w = tid >> 6;
      #pragma unroll
      for (int j = 0; j < 4; ++j) {
        float4 v; v.x = acc[j][0]; v.y = acc[j][1]; v.z = acc[j][2]; v.w = acc[j][3];
        *(float4*)&gredw[w * 256 + (rg * 4 + j) * 32 + bg * 4] = v;
      }
    }
    __syncthreads();
    // phase D: gates + state update (64 threads: jj in {0,1}, bb in [0,32))
    if (tid < 64) {
      float s0 = xg0, s1 = xg1, s2 = xg2, s3 = xg3;
      #pragma unroll
      for (int w = 0; w < 4; ++w) {
        s0 += gredw[w * 256 + (0 * 2 + jj) * 32 + bb];
        s1 += gredw[w * 256 + (1 * 2 + jj) * 32 + bb];
        s2 += gredw[w * 256 + (2 * 2 + jj) * 32 + bb];
        s3 += gredw[w * 256 + (3 * 2 + jj) * 32 + bb];
      }
      float gi = sigmoidf_(s0), gf = sigmoidf_(s1);
      float gg = tanhf(s2),     go = sigmoidf_(s3);
      c = gf * c + gi * gg;
      float h = go * tanhf(c);
      __hip_atomic_store(&hTnext[(j0 + jj) * B_ + bb], h,
                         __ATOMIC_RELAXED, __HIP_MEMORY_SCOPE_AGENT);
      hs[(size_t)(t * B_ + bb) * HID_ + j0 + jj] = h;   // plain: consumed after kernel end
    }
    if (t + 1 < T_) grid_barrier_tree(bar, (unsigned)t);
  }
}

// ---------------- kernel: attention per (t,b): softmax(masked scores), p_gen, alpha
__global__ void k_attn(const float* __restrict__ hs, const float* __restrict__ q_ws,
                       const float* __restrict__ enc_out, const int* __restrict__ enc_in,
                       const float* __restrict__ pge_W, const float* __restrict__ pge_b,
                       const float* __restrict__ pgd_W, const float* __restrict__ pgd_b,
                       float* __restrict__ alpha, float* __restrict__ pgen) {
  __shared__ float h_s[HID_], q_s[EMB_], aw_s[L_], al_s[96], red_s[256];
  int n = blockIdx.x, tid = threadIdx.x;   // 1024 blocks x 256 threads
  int b = n & 31;
  h_s[tid]       = hs[n * HID_ + tid];
  h_s[tid + 256] = hs[n * HID_ + 256 + tid];
  q_s[tid]       = q_ws[n * EMB_ + tid];
  if (tid < 96) al_s[tid] = 0.0f;
  __syncthreads();
  {
    int l = tid >> 2, part = tid & 3;
    const float* er = enc_out + (size_t)(b * L_ + l) * EMB_ + part * 64;
    const float* qp = q_s + part * 64;
    float acc = 0.f;
    #pragma unroll 8
    for (int i = 0; i < 64; ++i) acc += qp[i] * er[i];
    red_s[tid] = acc;
  }
  __syncthreads();
  if (tid < 64) {
    float s = red_s[tid * 4] + red_s[tid * 4 + 1] + red_s[tid * 4 + 2] + red_s[tid * 4 + 3];
    if (enc_in[b * L_ + tid] == 0) s = -1e30f;
    float mx = s;
    for (int off = 32; off >= 1; off >>= 1) mx = fmaxf(mx, __shfl_xor(mx, off));
    float e = expf(s - mx);
    float sum = e;
    for (int off = 32; off >= 1; off >>= 1) sum += __shfl_xor(sum, off);
    aw_s[tid] = e / sum;
  }
  __syncthreads();
  float cacc = 0.f;
  for (int l2 = 0; l2 < L_; ++l2)
    cacc += aw_s[l2] * enc_out[(size_t)(b * L_ + l2) * EMB_ + tid];
  red_s[tid] = cacc * pge_W[tid] + h_s[tid] * pgd_W[tid] + h_s[tid + 256] * pgd_W[tid + 256];
  __syncthreads();
  for (int s2 = 128; s2 >= 1; s2 >>= 1) {
    if (tid < s2) red_s[tid] += red_s[tid + s2];
    __syncthreads();
  }
  if (tid == 0) pgen[n] = 1.0f / (1.0f + expf(-(red_s[0] + pge_b[0] + pgd_b[0])));
  if (tid < 64) atomicAdd(&al_s[enc_in[b * L_ + tid]], aw_s[tid]);
  __syncthreads();
  if (tid < 96) alpha[n * 96 + tid] = al_s[tid];
}

// ---------------- kernel: output = pg*(h@linW^T + lb) + (1-pg)*(alpha@converter)
__global__ void k_out(const float* __restrict__ hs, const float* __restrict__ linW,
                      const float* __restrict__ linb, const float* __restrict__ conv,
                      const float* __restrict__ alpha, const float* __restrict__ pgen,
                      float* __restrict__ out) {
  __shared__ float As[32][68];
  __shared__ float Bs[32][68];
  __shared__ float alS[64 * 97];
  __shared__ float pg_s[64];
  int tid = threadIdx.x;
  int tx = tid & 15, ty = tid >> 4;
  int v0 = blockIdx.x * 64, n0 = blockIdx.y * 64;
  if (tid < 64) pg_s[tid] = pgen[n0 + tid];
  #pragma unroll
  for (int rep = 0; rep < 24; ++rep) {
    int idx = rep * 256 + tid;
    int row = idx / 96, jjx = idx - row * 96;
    alS[row * 97 + jjx] = alpha[(n0 + row) * 96 + jjx];
  }
  float acc1[4][4] = {};
  float acc2[4][4] = {};
  for (int k0 = 0; k0 < HID_; k0 += 32) {
    #pragma unroll
    for (int rep = 0; rep < 2; ++rep) {
      int idx = rep * 256 + tid;
      int row = idx >> 3, kq = (idx & 7) * 4;
      float4 a4 = *(const float4*)&hs[(n0 + row) * HID_ + k0 + kq];
      As[kq + 0][row] = a4.x; As[kq + 1][row] = a4.y;
      As[kq + 2][row] = a4.z; As[kq + 3][row] = a4.w;
      int vv = v0 + row; if (vv > V_ - 1) vv = V_ - 1;
      float4 b4 = *(const float4*)&linW[(size_t)vv * HID_ + k0 + kq];
      Bs[kq + 0][row] = b4.x; Bs[kq + 1][row] = b4.y;
      Bs[kq + 2][row] = b4.z; Bs[kq + 3][row] = b4.w;
    }
    __syncthreads();
    #pragma unroll
    for (int k = 0; k < 32; ++k) {
      float4 a4 = *(const float4*)&As[k][ty * 4];
      float4 b4 = *(const float4*)&Bs[k][tx * 4];
      float av[4] = {a4.x, a4.y, a4.z, a4.w};
      float bv[4] = {b4.x, b4.y, b4.z, b4.w};
      #pragma unroll
      for (int i = 0; i < 4; ++i)
        #pragma unroll
        for (int j = 0; j < 4; ++j)
          acc1[i][j] += av[i] * bv[j];
    }
    __syncthreads();
  }
  int vq = v0 + tx * 4;
  int vc = vq > V_ - 4 ? V_ - 4 : vq;
  for (int j = 0; j < NOBJ_; ++j) {
    float4 c4 = *(const float4*)&conv[(size_t)j * V_ + vc];
    float cv[4] = {c4.x, c4.y, c4.z, c4.w};
    #pragma unroll
    for (int i = 0; i < 4; ++i) {
      float av = alS[(ty * 4 + i) * 97 + j];
      #pragma unroll
      for (int jjx = 0; jjx < 4; ++jjx) acc2[i][jjx] += av * cv[jjx];
    }
  }
  if (vq + 3 < V_) {
    float4 lb4 = *(const float4*)&linb[vq];
    float lb[4] = {lb4.x, lb4.y, lb4.z, lb4.w};
    #pragma unroll
    for (int i = 0; i < 4; ++i) {
      int row = ty * 4 + i;
      float pg = pg_s[row];
      float4 o;
      o.x = pg * (acc1[i][0] + lb[0]) + (1.0f - pg) * acc2[i][0];
      o.y = pg * (acc1[i][1] + lb[1]) + (1.0f - pg) * acc2[i][1];
      o.z = pg * (acc1[i][2] + lb[2]) + (1.0f - pg) * acc2[i][2];
      o.w = pg * (acc1[i][3] + lb[3]) + (1.0f - pg) * acc2[i][3];
      *(float4*)&out[(size_t)(n0 + row) * V_ + vq] = o;
    }
  }
}

extern "C" void kernel_launch(void* const* d_in, const int* in_sizes, int n_in,
                              void* d_out, int out_size, void* d_ws, size_t ws_size,
                              hipStream_t stream) {
  const float* features = (const float*)d_in[0];
  const int*   captions = (const int*)d_in[1];
  const int*   enc_in   = (const int*)d_in[3];
  const float* enc_out  = (const float*)d_in[4];
  const float* embed_W  = (const float*)d_in[5];
  const float* W_ih     = (const float*)d_in[6];
  const float* W_hh     = (const float*)d_in[7];
  const float* b_ih     = (const float*)d_in[8];
  const float* b_hh     = (const float*)d_in[9];
  const float* linear_W = (const float*)d_in[10];
  const float* linear_b = (const float*)d_in[11];
  const float* attn_W   = (const float*)d_in[12];
  const float* attn_b   = (const float*)d_in[13];
  const float* pge_W    = (const float*)d_in[14];
  const float* pge_b    = (const float*)d_in[15];
  const float* pgd_W    = (const float*)d_in[16];
  const float* pgd_b    = (const float*)d_in[17];
  const float* conv     = (const float*)d_in[18];
  float* out = (float*)d_out;

  float* ws   = (float*)d_ws;
  float* X    = ws;                  // 1024*256
  float* Xg   = X    + 262144;       // 1024*2048
  float* hTb  = Xg   + 2097152;      // 2*512*32
  float* hsb  = hTb  + 32768;        // 1024*512
  float* qws  = hsb  + 524288;       // 1024*256
  float* alp  = qws  + 262144;       // 1024*96
  float* pgn  = alp  + 98304;        // 1024
  unsigned* bar = (unsigned*)(pgn + 1024);   // 320 words: 16 leaves(64B apart)+root+gen

  hipMemsetAsync(bar, 0, 320 * sizeof(unsigned), stream);
  k_gather <<<1024, 256, 0, stream>>>(features, captions, embed_W, X);
  k_gemm_bt<<<dim3(32, 16), 256, 0, stream>>>(X, W_ih, b_ih, b_hh, Xg, NROWS, G4_, EMB_);
  {
    const float* Xg_c = Xg;
    const float* Whh_c = W_hh;
    float* hTb_p = hTb;
    float* hsb_p = hsb;
    unsigned* bar_p = bar;
    void* args[] = { (void*)&Xg_c, (void*)&Whh_c, (void*)&hTb_p, (void*)&hsb_p,
                     (void*)&bar_p };
    hipLaunchCooperativeKernel((const void*)k_lstm_coop, dim3(256), dim3(256),
                               args, 0, stream);
  }
  k_gemm_bt<<<dim3(4, 16), 256, 0, stream>>>(hsb, attn_W, attn_b, nullptr, qws, NROWS, EMB_, HID_);
  k_attn   <<<1024, 256, 0, stream>>>(hsb, qws, enc_out, enc_in, pge_W, pge_b, pgd_W, pgd_b, alp, pgn);
  k_out    <<<dim3(469, 16), 256, 0, stream>>>(hsb, linear_W, linear_b, conv, alp, pgn, out);
}

// Round 2
// 941.020 us; speedup vs baseline: 1.8420x; 1.1770x over previous
//
#include <hip/hip_runtime.h>
#include <hip/hip_bf16.h>
#include <math.h>

#define B_    32
#define T_    32
#define L_    64
#define EMB_  256
#define HID_  512
#define G4_   2048   // 4*HID
#define V_    30000
#define NOBJ_ 91
#define NROWS 1024   // T_*B_

#define NLEAF_    16u
#define BLK_PER_LEAF_ 16u

typedef short  s16x8 __attribute__((ext_vector_type(8)));
typedef float  f32x4 __attribute__((ext_vector_type(4)));
typedef unsigned short us8 __attribute__((ext_vector_type(8)));

__device__ __forceinline__ float sigmoidf_(float x) { return 1.0f / (1.0f + expf(-x)); }

// round-to-nearest-even fp32 -> bf16 bits
__device__ __forceinline__ unsigned short bf16rn(float x) {
  unsigned u = __float_as_uint(x);
  unsigned r = u + 0x7FFFu + ((u >> 16) & 1u);
  return (unsigned short)(r >> 16);
}
__device__ __forceinline__ float bf16tof(unsigned short h) {
  return __uint_as_float(((unsigned)h) << 16);
}

// Fence-free tree grid barrier (round-1 win; unchanged). Monotonic counters,
// RELAXED agent-scope atomics -> no buffer_wbl2/buffer_inv storm.
__device__ __forceinline__ void grid_barrier_tree(unsigned* bar, unsigned t) {
  __syncthreads();
  if (threadIdx.x == 0) {
    const unsigned target = t + 1u;
    asm volatile("s_waitcnt vmcnt(0)" ::: "memory");
    unsigned* lc = bar + (blockIdx.x & (NLEAF_ - 1u)) * 16u;
    unsigned a = __hip_atomic_fetch_add(lc, 1u, __ATOMIC_RELAXED, __HIP_MEMORY_SCOPE_AGENT) + 1u;
    if (a == target * BLK_PER_LEAF_) {
      unsigned r = __hip_atomic_fetch_add(bar + 256, 1u, __ATOMIC_RELAXED, __HIP_MEMORY_SCOPE_AGENT) + 1u;
      if (r == target * NLEAF_) {
        __hip_atomic_store(bar + 272, target, __ATOMIC_RELAXED, __HIP_MEMORY_SCOPE_AGENT);
      }
    }
    unsigned cur;
    do {
      __builtin_amdgcn_s_sleep(1);
      cur = __hip_atomic_load(bar + 272, __ATOMIC_RELAXED, __HIP_MEMORY_SCOPE_AGENT);
    } while (cur < target);
  }
  __syncthreads();
}

// ---------------- kernel 1: gather embeddings, time-major X[n][256], n = t*32+b
__global__ void k_gather(const float* __restrict__ features,
                         const int*   __restrict__ captions,
                         const float* __restrict__ embed_W,
                         float* __restrict__ X) {
  int n = blockIdx.x, e = threadIdx.x;          // 1024 blocks x 256 threads
  int t = n >> 5, b = n & 31;
  float v;
  if (t == 0) v = features[b * EMB_ + e];
  else        v = embed_W[captions[b * T_ + (t - 1)] * EMB_ + e];
  X[n * EMB_ + e] = v;
}

// ---------------- generic tiled f32 GEMM: C[M,N] = A[M,K] @ B[N,K]^T (+bias1[n]+bias2[n])
__global__ void k_gemm_bt(const float* __restrict__ A, const float* __restrict__ Bm,
                          const float* __restrict__ bias1, const float* __restrict__ bias2,
                          float* __restrict__ C, int M, int N, int K) {
  __shared__ float As[32][68];
  __shared__ float Bs[32][68];
  int tid = threadIdx.x;
  int tx = tid & 15, ty = tid >> 4;
  int n0 = blockIdx.x * 64, m0 = blockIdx.y * 64;
  float acc[4][4] = {};
  for (int k0 = 0; k0 < K; k0 += 32) {
    #pragma unroll
    for (int rep = 0; rep < 2; ++rep) {
      int idx = rep * 256 + tid;          // [0,512)
      int row = idx >> 3, kq = (idx & 7) * 4;
      float4 a4 = *(const float4*)&A[(m0 + row) * K + k0 + kq];
      As[kq + 0][row] = a4.x; As[kq + 1][row] = a4.y;
      As[kq + 2][row] = a4.z; As[kq + 3][row] = a4.w;
      float4 b4 = *(const float4*)&Bm[(n0 + row) * K + k0 + kq];
      Bs[kq + 0][row] = b4.x; Bs[kq + 1][row] = b4.y;
      Bs[kq + 2][row] = b4.z; Bs[kq + 3][row] = b4.w;
    }
    __syncthreads();
    #pragma unroll
    for (int k = 0; k < 32; ++k) {
      float4 a4 = *(const float4*)&As[k][ty * 4];
      float4 b4 = *(const float4*)&Bs[k][tx * 4];
      float av[4] = {a4.x, a4.y, a4.z, a4.w};
      float bv[4] = {b4.x, b4.y, b4.z, b4.w};
      #pragma unroll
      for (int i = 0; i < 4; ++i)
        #pragma unroll
        for (int j = 0; j < 4; ++j)
          acc[i][j] += av[i] * bv[j];
    }
    __syncthreads();
  }
  int nn = n0 + tx * 4;
  float bb[4] = {0.f, 0.f, 0.f, 0.f};
  if (bias1) {
    #pragma unroll
    for (int j = 0; j < 4; ++j) bb[j] += bias1[nn + j];
  }
  if (bias2) {
    #pragma unroll
    for (int j = 0; j < 4; ++j) bb[j] += bias2[nn + j];
  }
  #pragma unroll
  for (int i = 0; i < 4; ++i) {
    int m = m0 + ty * 4 + i;
    float4 o;
    o.x = acc[i][0] + bb[0]; o.y = acc[i][1] + bb[1];
    o.z = acc[i][2] + bb[2]; o.w = acc[i][3] + bb[3];
    *(float4*)&C[m * N + nn] = o;
  }
}

// ---------------- split f32 -> (hi, lo) bf16 arrays, vectorized, grid-stride
__global__ void k_split(const float* __restrict__ in, unsigned short* __restrict__ hi,
                        unsigned short* __restrict__ lo, int n4) {
  int i = blockIdx.x * blockDim.x + threadIdx.x;
  int stride = gridDim.x * blockDim.x;
  for (; i < n4; i += stride) {
    float4 v = ((const float4*)in)[i];
    ushort4 h, l;
    h.x = bf16rn(v.x); l.x = bf16rn(v.x - bf16tof(h.x));
    h.y = bf16rn(v.y); l.y = bf16rn(v.y - bf16tof(h.y));
    h.z = bf16rn(v.z); l.z = bf16rn(v.z - bf16tof(h.z));
    h.w = bf16rn(v.w); l.w = bf16rn(v.w - bf16tof(h.w));
    ((ushort4*)hi)[i] = h;
    ((ushort4*)lo)[i] = l;
  }
}

// ---------------- transpose converter [91][30000] f32 -> [30000][96] bf16 hi/lo (o padded w/ 0)
__global__ void k_convt(const float* __restrict__ conv, unsigned short* __restrict__ cvh,
                        unsigned short* __restrict__ cvl) {
  __shared__ float t[NOBJ_][65];
  int tid = threadIdx.x;
  int v0 = blockIdx.x * 64;
  {
    int c = tid & 63, og = tid >> 6;
    for (int o = og; o < NOBJ_; o += 4) {
      int col = v0 + c;
      t[o][c] = (col < V_) ? conv[(size_t)o * V_ + col] : 0.f;
    }
  }
  __syncthreads();
  int row = tid >> 2, part = tid & 3;
  int gr = v0 + row;
  if (gr < V_) {
    unsigned short hb[24], lb[24];
    #pragma unroll
    for (int j = 0; j < 24; ++j) {
      int o = part * 24 + j;
      float x = (o < NOBJ_) ? t[o][row] : 0.f;
      unsigned short h = bf16rn(x);
      hb[j] = h;
      lb[j] = bf16rn(x - bf16tof(h));
    }
    size_t base = (size_t)gr * 96 + part * 24;
    #pragma unroll
    for (int k = 0; k < 3; ++k) {
      *(us8*)(cvh + base + k * 8) = *(us8*)&hb[k * 8];
      *(us8*)(cvl + base + k * 8) = *(us8*)&lb[k * 8];
    }
  }
}

// ---------------- cooperative persistent LSTM (round-1 structure, unchanged)
__global__ __launch_bounds__(256) void k_lstm_coop(
    const float* __restrict__ Xg,    // [1024][2048] input gates (time-major)
    const float* __restrict__ W_hh,  // [2048][512]
    float* __restrict__ hTbuf,       // [2][512][32]
    float* __restrict__ hs,          // [1024][512]
    unsigned* __restrict__ bar) {
  __shared__ float wt_s[512 * 8];
  __shared__ float gredw[4 * 8 * 32];
  const int m = blockIdx.x;
  const int j0 = 2 * m;
  const int tid = threadIdx.x;
  const int kc = tid >> 4;
  const int rg = (tid >> 3) & 1;
  const int bg = tid & 7;
  const int jj = tid >> 5, bb = tid & 31;

  {
    int q = tid >> 5, lane = tid & 31;
    const float* src = W_hh + (size_t)((q >> 1) * 512 + j0 + (q & 1)) * HID_;
    for (int kk = 0; kk < 16; ++kk) {
      int k = kk * 32 + lane;
      wt_s[k * 8 + q] = src[k];
    }
  }
  __syncthreads();

  float c = 0.0f;
  for (int t = 0; t < T_; ++t) {
    const float* hTcur = hTbuf + (t & 1) * (HID_ * B_);
    float* hTnext      = hTbuf + ((t + 1) & 1) * (HID_ * B_);
    float xg0 = 0.f, xg1 = 0.f, xg2 = 0.f, xg3 = 0.f;
    if (tid < 64) {
      const float* xp = Xg + (size_t)(t * B_ + bb) * G4_ + j0 + jj;
      xg0 = xp[0]; xg1 = xp[512]; xg2 = xp[1024]; xg3 = xp[1536];
    }
    float acc[4][4] = {};
    if (t > 0) {
      #pragma unroll 4
      for (int kk = 0; kk < 32; ++kk) {
        const unsigned long long* hp =
            (const unsigned long long*)&hTcur[kk * 512 + kc * 32 + 4 * bg];
        unsigned long long u0 = __hip_atomic_load(hp,     __ATOMIC_RELAXED, __HIP_MEMORY_SCOPE_AGENT);
        unsigned long long u1 = __hip_atomic_load(hp + 1, __ATOMIC_RELAXED, __HIP_MEMORY_SCOPE_AGENT);
        union { unsigned long long u; float f[2]; } c0, c1;
        c0.u = u0; c1.u = u1;
        float hx = c0.f[0], hy = c0.f[1], hz = c1.f[0], hw = c1.f[1];
        float4 w4 = *(const float4*)&wt_s[(kk * 16 + kc) * 8 + 4 * rg];
        acc[0][0] += w4.x * hx; acc[0][1] += w4.x * hy; acc[0][2] += w4.x * hz; acc[0][3] += w4.x * hw;
        acc[1][0] += w4.y * hx; acc[1][1] += w4.y * hy; acc[1][2] += w4.y * hz; acc[1][3] += w4.y * hw;
        acc[2][0] += w4.z * hx; acc[2][1] += w4.z * hy; acc[2][2] += w4.z * hz; acc[2][3] += w4.z * hw;
        acc[3][0] += w4.w * hx; acc[3][1] += w4.w * hy; acc[3][2] += w4.w * hz; acc[3][3] += w4.w * hw;
      }
    }
    #pragma unroll
    for (int j = 0; j < 4; ++j)
      #pragma unroll
      for (int i = 0; i < 4; ++i) {
        acc[j][i] += __shfl_xor(acc[j][i], 16);
        acc[j][i] += __shfl_xor(acc[j][i], 32);
      }
    if ((tid & 63) < 16) {
      int w = tid >> 6;
      #pragma unroll
      for (int j = 0; j < 4; ++j) {
        float4 v; v.x = acc[j][0]; v.y = acc[j][1]; v.z = acc[j][2]; v.w = acc[j][3];
        *(float4*)&gredw[w * 256 + (rg * 4 + j) * 32 + bg * 4] = v;
      }
    }
    __syncthreads();
    if (tid < 64) {
      float s0 = xg0, s1 = xg1, s2 = xg2, s3 = xg3;
      #pragma unroll
      for (int w = 0; w < 4; ++w) {
        s0 += gredw[w * 256 + (0 * 2 + jj) * 32 + bb];
        s1 += gredw[w * 256 + (1 * 2 + jj) * 32 + bb];
        s2 += gredw[w * 256 + (2 * 2 + jj) * 32 + bb];
        s3 += gredw[w * 256 + (3 * 2 + jj) * 32 + bb];
      }
      float gi = sigmoidf_(s0), gf = sigmoidf_(s1);
      float gg = tanhf(s2),     go = sigmoidf_(s3);
      c = gf * c + gi * gg;
      float h = go * tanhf(c);
      __hip_atomic_store(&hTnext[(j0 + jj) * B_ + bb], h,
                         __ATOMIC_RELAXED, __HIP_MEMORY_SCOPE_AGENT);
      hs[(size_t)(t * B_ + bb) * HID_ + j0 + jj] = h;
    }
    if (t + 1 < T_) grid_barrier_tree(bar, (unsigned)t);
  }
}

// ---------------- attention; now emits alpha as bf16 hi/lo (for MFMA consumer)
__global__ void k_attn(const float* __restrict__ hs, const float* __restrict__ q_ws,
                       const float* __restrict__ enc_out, const int* __restrict__ enc_in,
                       const float* __restrict__ pge_W, const float* __restrict__ pge_b,
                       const float* __restrict__ pgd_W, const float* __restrict__ pgd_b,
                       unsigned short* __restrict__ alph, unsigned short* __restrict__ alpl,
                       float* __restrict__ pgen) {
  __shared__ float h_s[HID_], q_s[EMB_], aw_s[L_], al_s[96], red_s[256];
  int n = blockIdx.x, tid = threadIdx.x;   // 1024 blocks x 256 threads
  int b = n & 31;
  h_s[tid]       = hs[n * HID_ + tid];
  h_s[tid + 256] = hs[n * HID_ + 256 + tid];
  q_s[tid]       = q_ws[n * EMB_ + tid];
  if (tid < 96) al_s[tid] = 0.0f;
  __syncthreads();
  {
    int l = tid >> 2, part = tid & 3;
    const float* er = enc_out + (size_t)(b * L_ + l) * EMB_ + part * 64;
    const float* qp = q_s + part * 64;
    float acc = 0.f;
    #pragma unroll 8
    for (int i = 0; i < 64; ++i) acc += qp[i] * er[i];
    red_s[tid] = acc;
  }
  __syncthreads();
  if (tid < 64) {
    float s = red_s[tid * 4] + red_s[tid * 4 + 1] + red_s[tid * 4 + 2] + red_s[tid * 4 + 3];
    if (enc_in[b * L_ + tid] == 0) s = -1e30f;
    float mx = s;
    for (int off = 32; off >= 1; off >>= 1) mx = fmaxf(mx, __shfl_xor(mx, off));
    float e = expf(s - mx);
    float sum = e;
    for (int off = 32; off >= 1; off >>= 1) sum += __shfl_xor(sum, off);
    aw_s[tid] = e / sum;
  }
  __syncthreads();
  float cacc = 0.f;
  for (int l2 = 0; l2 < L_; ++l2)
    cacc += aw_s[l2] * enc_out[(size_t)(b * L_ + l2) * EMB_ + tid];
  red_s[tid] = cacc * pge_W[tid] + h_s[tid] * pgd_W[tid] + h_s[tid + 256] * pgd_W[tid + 256];
  __syncthreads();
  for (int s2 = 128; s2 >= 1; s2 >>= 1) {
    if (tid < s2) red_s[tid] += red_s[tid + s2];
    __syncthreads();
  }
  if (tid == 0) pgen[n] = 1.0f / (1.0f + expf(-(red_s[0] + pge_b[0] + pgd_b[0])));
  if (tid < 64) atomicAdd(&al_s[enc_in[b * L_ + tid]], aw_s[tid]);
  __syncthreads();
  if (tid < 96) {
    float a = al_s[tid];
    unsigned short h = bf16rn(a);
    alph[n * 96 + tid] = h;
    alpl[n * 96 + tid] = bf16rn(a - bf16tof(h));
  }
}

// ---------------- fused output via split-bf16 MFMA:
// out[n][v] = pg[n]*( (hs@linW^T)[n][v] + linb[v] ) + (1-pg[n])*(alpha@convT^T)[n][v]
// 3-term bf16x3 emulation: hi*hi + hi*lo + lo*hi accumulated in fp32 MFMA.
// Block: 256 thr = 4 waves; tile 32 rows x 256 cols (wave w owns cols w*64..+63).
// mfma_f32_16x16x32_bf16 frags: A row=lane&15,k=8*(lane>>4)+e; B col=lane&15 same k;
// D col=lane&15,row=4*(lane>>4)+reg  [m89-verified].
__global__ __launch_bounds__(256) void k_out_mfma(
    const unsigned short* __restrict__ hsh, const unsigned short* __restrict__ hsl,  // [1024][512]
    const unsigned short* __restrict__ lwh, const unsigned short* __restrict__ lwl,  // [30000][512]
    const unsigned short* __restrict__ alph, const unsigned short* __restrict__ alpl,// [1024][96]
    const unsigned short* __restrict__ cvh, const unsigned short* __restrict__ cvl,  // [30000][96]
    const float* __restrict__ linb, const float* __restrict__ pgen,
    float* __restrict__ out) {
  const int tid  = threadIdx.x;
  const int wave = tid >> 6, lane = tid & 63;
  const int l15  = lane & 15, l4 = lane >> 4;
  const int n0   = blockIdx.x * 32;                 // row tile (x fastest: shares lW slice in L2)
  const int v0   = blockIdx.y * 256 + wave * 64;    // col tile for this wave

  int bcol[4];
  #pragma unroll
  for (int n = 0; n < 4; ++n) {
    int c = v0 + n * 16 + l15;
    bcol[n] = (c < V_) ? c : (V_ - 1);
  }

  f32x4 acc1[2][4] = {};
  f32x4 acc2[2][4] = {};

  // ---- regular logits: K = 512
  for (int k0 = 0; k0 < HID_; k0 += 32) {
    s16x8 aH[2], aL[2];
    #pragma unroll
    for (int m = 0; m < 2; ++m) {
      int off = (n0 + m * 16 + l15) * HID_ + k0 + l4 * 8;
      aH[m] = *(const s16x8*)(hsh + off);
      aL[m] = *(const s16x8*)(hsl + off);
    }
    #pragma unroll
    for (int n = 0; n < 4; ++n) {
      size_t off = (size_t)bcol[n] * HID_ + k0 + l4 * 8;
      s16x8 bH = *(const s16x8*)(lwh + off);
      s16x8 bL = *(const s16x8*)(lwl + off);
      #pragma unroll
      for (int m = 0; m < 2; ++m) {
        acc1[m][n] = __builtin_amdgcn_mfma_f32_16x16x32_bf16(aH[m], bH, acc1[m][n], 0, 0, 0);
        acc1[m][n] = __builtin_amdgcn_mfma_f32_16x16x32_bf16(aH[m], bL, acc1[m][n], 0, 0, 0);
        acc1[m][n] = __builtin_amdgcn_mfma_f32_16x16x32_bf16(aL[m], bH, acc1[m][n], 0, 0, 0);
      }
    }
  }

  // ---- pointer logits: K = 96 (91 padded with zeros)
  #pragma unroll
  for (int k0 = 0; k0 < 96; k0 += 32) {
    s16x8 aH[2], aL[2];
    #pragma unroll
    for (int m = 0; m < 2; ++m) {
      int off = (n0 + m * 16 + l15) * 96 + k0 + l4 * 8;
      aH[m] = *(const s16x8*)(alph + off);
      aL[m] = *(const s16x8*)(alpl + off);
    }
    #pragma unroll
    for (int n = 0; n < 4; ++n) {
      size_t off = (size_t)bcol[n] * 96 + k0 + l4 * 8;
      s16x8 bH = *(const s16x8*)(cvh + off);
      s16x8 bL = *(const s16x8*)(cvl + off);
      #pragma unroll
      for (int m = 0; m < 2; ++m) {
        acc2[m][n] = __builtin_amdgcn_mfma_f32_16x16x32_bf16(aH[m], bH, acc2[m][n], 0, 0, 0);
        acc2[m][n] = __builtin_amdgcn_mfma_f32_16x16x32_bf16(aH[m], bL, acc2[m][n], 0, 0, 0);
        acc2[m][n] = __builtin_amdgcn_mfma_f32_16x16x32_bf16(aL[m], bH, acc2[m][n], 0, 0, 0);
      }
    }
  }

  // ---- epilogue
  float lb[4];
  #pragma unroll
  for (int n = 0; n < 4; ++n) {
    int col = v0 + n * 16 + l15;
    lb[n] = (col < V_) ? linb[col] : 0.f;
  }
  #pragma unroll
  for (int m = 0; m < 2; ++m) {
    #pragma unroll
    for (int r = 0; r < 4; ++r) {
      int row = n0 + m * 16 + l4 * 4 + r;
      float pg = pgen[row];
      #pragma unroll
      for (int n = 0; n < 4; ++n) {
        int col = v0 + n * 16 + l15;
        if (col < V_) {
          float o = pg * (acc1[m][n][r] + lb[n]) + (1.0f - pg) * acc2[m][n][r];
          out[(size_t)row * V_ + col] = o;
        }
      }
    }
  }
}

extern "C" void kernel_launch(void* const* d_in, const int* in_sizes, int n_in,
                              void* d_out, int out_size, void* d_ws, size_t ws_size,
                              hipStream_t stream) {
  const float* features = (const float*)d_in[0];
  const int*   captions = (const int*)d_in[1];
  const int*   enc_in   = (const int*)d_in[3];
  const float* enc_out  = (const float*)d_in[4];
  const float* embed_W  = (const float*)d_in[5];
  const float* W_ih     = (const float*)d_in[6];
  const float* W_hh     = (const float*)d_in[7];
  const float* b_ih     = (const float*)d_in[8];
  const float* b_hh     = (const float*)d_in[9];
  const float* linear_W = (const float*)d_in[10];
  const float* linear_b = (const float*)d_in[11];
  const float* attn_W   = (const float*)d_in[12];
  const float* attn_b   = (const float*)d_in[13];
  const float* pge_W    = (const float*)d_in[14];
  const float* pge_b    = (const float*)d_in[15];
  const float* pgd_W    = (const float*)d_in[16];
  const float* pgd_b    = (const float*)d_in[17];
  const float* conv     = (const float*)d_in[18];
  float* out = (float*)d_out;

  float* ws   = (float*)d_ws;
  float* X    = ws;                  // 262144 f
  float* Xg   = X    + 262144;       // 2097152 f
  float* hTb  = Xg   + 2097152;      // 32768 f
  float* hsb  = hTb  + 32768;        // 524288 f
  float* qws  = hsb  + 524288;       // 262144 f
  float* pgn  = qws  + 262144;       // 1024 f
  unsigned* bar = (unsigned*)(pgn + 1024);           // 1024 u32 reserved
  unsigned short* lwh  = (unsigned short*)(bar + 1024);
  unsigned short* lwl  = lwh  + 15360000;            // 30000*512
  unsigned short* hsh  = lwl  + 15360000;
  unsigned short* hsl  = hsh  + 524288;              // 1024*512
  unsigned short* alph = hsl  + 524288;
  unsigned short* alpl = alph + 98304;               // 1024*96
  unsigned short* cvh  = alpl + 98304;
  unsigned short* cvl  = cvh  + 2880000;             // 30000*96

  hipMemsetAsync(bar, 0, 1024 * sizeof(unsigned), stream);
  // weight preprocessing (no deps on LSTM)
  k_split <<<2048, 256, 0, stream>>>(linear_W, lwh, lwl, 15360000 / 4);
  k_convt <<<469, 256, 0, stream>>>(conv, cvh, cvl);

  k_gather <<<1024, 256, 0, stream>>>(features, captions, embed_W, X);
  k_gemm_bt<<<dim3(32, 16), 256, 0, stream>>>(X, W_ih, b_ih, b_hh, Xg, NROWS, G4_, EMB_);
  {
    const float* Xg_c = Xg;
    const float* Whh_c = W_hh;
    float* hTb_p = hTb;
    float* hsb_p = hsb;
    unsigned* bar_p = bar;
    void* args[] = { (void*)&Xg_c, (void*)&Whh_c, (void*)&hTb_p, (void*)&hsb_p,
                     (void*)&bar_p };
    hipLaunchCooperativeKernel((const void*)k_lstm_coop, dim3(256), dim3(256),
                               args, 0, stream);
  }
  k_split <<<512, 256, 0, stream>>>(hsb, hsh, hsl, 524288 / 4);
  k_gemm_bt<<<dim3(4, 16), 256, 0, stream>>>(hsb, attn_W, attn_b, nullptr, qws, NROWS, EMB_, HID_);
  k_attn   <<<1024, 256, 0, stream>>>(hsb, qws, enc_out, enc_in, pge_W, pge_b, pgd_W, pgd_b, alph, alpl, pgn);
  k_out_mfma<<<dim3(32, 118), 256, 0, stream>>>(hsh, hsl, lwh, lwl, alph, alpl, cvh, cvl,
                                                linear_b, pgn, out);
}